// Round 1
// 3074.112 us; speedup vs baseline: 1.1407x; 1.1407x over previous
//
#include <hip/hip_runtime.h>
#include <hip/hip_cooperative_groups.h>
#include <cmath>

namespace cg = cooperative_groups;

// Problem constants
constexpr int B_  = 128, L_ = 128, I_ = 256, H_ = 256;
constexpr int G4_ = 1024;          // 4*H
constexpr int K_  = 512;           // I+H == H+H
constexpr int NBLK = 256;          // 64 unit-tiles x 4 batch-tiles (1 block/CU)
constexpr int NTHR = 512;          // 8 waves/CU
constexpr int BT = 32;             // batch rows per WG
constexpr int GR = 16;             // gate rows per WG (4 units x 4 gates)

// ws layout (float offsets)
constexpr int WSTD0 = 0;
constexpr int WSTD1 = 524288;
constexpr int BSTD0 = 1048576;
constexpr int BSTD1 = BSTD0 + 1024;
constexpr int HB0   = BSTD1 + 1024;   // 2 ping-pong buffers of 128*256
constexpr int HB1   = HB0 + 65536;
constexpr int KLP   = HB1 + 65536;    // 256 partials
constexpr int CNT   = KLP + 256;      // 16 counters (stride 32 u32) + epoch @ [512]

// out layout (float offsets)
constexpr int HF_OFF = B_*L_*H_;           // 4194304
constexpr int CF_OFF = HF_OFF + 2*B_*H_;   // 4259840
constexpr int KL_OFF = CF_OFF + 2*B_*H_;   // 4325376

__device__ __forceinline__ float sigm(float v) { return 1.0f / (1.0f + expf(-v)); }

// Coherent (L1/L2-bypassing) 16B load — data comes from L3, which agent-scope
// atomic stores write through to. Consumer must drain vmcnt before use.
__device__ __forceinline__ float4 ld_cohere(const float* p) {
  float4 v;
  asm volatile("global_load_dwordx4 %0, %1, off sc0 sc1"
               : "=v"(v) : "v"(p) : "memory");
  return v;
}

__device__ __forceinline__ void vm_drain() {
  asm volatile("s_waitcnt vmcnt(0)" ::: "memory");
}

__global__ __launch_bounds__(NTHR, 1) void vlstm(
    const float* __restrict__ x,
    const float* __restrict__ wmu0, const float* __restrict__ wlv0,
    const float* __restrict__ bmu0, const float* __restrict__ blv0,
    const float* __restrict__ wmu1, const float* __restrict__ wlv1,
    const float* __restrict__ bmu1, const float* __restrict__ blv1,
    const float* __restrict__ epsw0, const float* __restrict__ epsb0,
    const float* __restrict__ epsw1, const float* __restrict__ epsb1,
    float* __restrict__ out, float* __restrict__ ws)
{
  cg::grid_group grid = cg::this_grid();
  const int tid = threadIdx.x;
  const int g   = blockIdx.x;
  const int bt  = g >> 6;            // 0..3
  const int ut  = g & 63;            // 0..63
  const int b0  = bt * BT;
  const int u0  = ut * 4;

  // pad 4: row stride mod 32 banks = 4 -> 8-row wave groups hit disjoint banks
  __shared__ float Xs [BT][260];     // x_t tile (pre-staged one step ahead)
  __shared__ float H0s[BT][260];     // h0prev tile
  __shared__ float H1s[BT][260];     // h1prev tile
  __shared__ float Wsh[GR][516];     // full-K W tile, single-buffered, reg-refilled
  __shared__ float red[NTHR];

  float* wstd0 = ws + WSTD0;
  float* wstd1 = ws + WSTD1;
  float* bstd0 = ws + BSTD0;
  float* bstd1 = ws + BSTD1;
  float* hb0   = ws + HB0;
  float* hb1   = ws + HB1;
  float* klp   = ws + KLP;
  unsigned* cnt = (unsigned*)(ws + CNT);   // [0..480 step 32] arrive; [512] epoch

  // ---------------- pre-phase: stds, KL partials, zero h buffers ----------------
  const int gid = g * NTHR + tid;
  const int gsz = NBLK * NTHR;   // 131072
  float kl = 0.f;
  for (int i = gid; i < 524288; i += gsz) {
    float l0 = wlv0[i], l1 = wlv1[i];
    float m0 = wmu0[i], m1 = wmu1[i];
    wstd0[i] = expf(0.5f * l0);
    wstd1[i] = expf(0.5f * l1);
    kl += 0.5f * (m0*m0 + expf(l0) - l0) + 0.5f * (m1*m1 + expf(l1) - l1);
  }
  for (int i = gid; i < G4_; i += gsz) {
    float l0 = blv0[i], l1 = blv1[i];
    float m0 = bmu0[i], m1 = bmu1[i];
    bstd0[i] = expf(0.5f * l0);
    bstd1[i] = expf(0.5f * l1);
    kl += 0.5f * (m0*m0 + expf(l0) - l0) + 0.5f * (m1*m1 + expf(l1) - l1);
  }
  for (int i = gid; i < 32768; i += gsz) {
    hb0[i] = 0.f; hb0[32768 + i] = 0.f;
    hb1[i] = 0.f; hb1[32768 + i] = 0.f;
  }
  if (gid < 544) cnt[gid] = 0u;
  red[tid] = kl;
  __syncthreads();
  for (int s = NTHR / 2; s > 0; s >>= 1) {
    if (tid < s) red[tid] += red[tid + s];
    __syncthreads();
  }
  if (tid == 0) klp[g] = red[0];
  grid.sync();   // publishes wstd/bstd, hb zeros, klp, counters device-wide

  // compute mapping: wave = 8 batch rows x 8 gate rows (minimizes LDS row pulls)
  const int wid  = tid >> 6;
  const int lane = tid & 63;
  const int b_l  = ((wid & 3) << 3) | (lane >> 3);      // 0..31
  const int rr   = ((wid >> 2) << 3) | (lane & 7);      // 0..15
  const int gq   = lane & 3;                            // gate: 0=i 1=f 2=g 3=o
  const int un   = rr >> 2;                             // unit 0..3
  const int jrow = gq * H_ + u0 + un;                   // global gate row
  const int bglob = b0 + b_l;
  const int uglob = u0 + un;

  float c0reg = 0.f, c1reg = 0.f;    // cell state lives in g==0 lanes

  // W-tile source prefetch: 16 rows x 512 cols, 4 float4 triplets per thread
  auto issueW = [&](int layer, int t, float4* mu, float4* sd, float4* ep) {
    const float* wmu  = layer ? wmu1  : wmu0;
    const float* wstd = layer ? wstd1 : wstd0;
    const float* epsw = layer ? epsw1 : epsw0;
    #pragma unroll
    for (int p = 0; p < 4; p++) {
      int q = p * NTHR + tid;          // 0..2047
      int row = q >> 7, c = q & 127;
      int jr  = (row & 3) * H_ + u0 + (row >> 2);
      mu[p] = *(const float4*)(wmu  + jr * K_ + c * 4);
      sd[p] = *(const float4*)(wstd + jr * K_ + c * 4);
      ep[p] = *(const float4*)(epsw + (t * G4_ + jr) * K_ + c * 4);
    }
  };
  auto writeW = [&](const float4* mu, const float4* sd, const float4* ep) {
    #pragma unroll
    for (int p = 0; p < 4; p++) {
      int q = p * NTHR + tid;
      int row = q >> 7, c = q & 127;
      float4 wv;
      wv.x = fmaf(ep[p].x, sd[p].x, mu[p].x);
      wv.y = fmaf(ep[p].y, sd[p].y, mu[p].y);
      wv.z = fmaf(ep[p].z, sd[p].z, mu[p].z);
      wv.w = fmaf(ep[p].w, sd[p].w, mu[p].w);
      *(float4*)&Wsh[row][c * 4] = wv;
    }
  };
  // 256-wide dot of an A row against 256 cols of this thread's W row
  auto dotp = [&](const float* Ap, const float* Wp) -> float {
    const float4* A4 = (const float4*)Ap;
    const float4* W4 = (const float4*)Wp;
    float pa = 0.f, qa = 0.f;
    #pragma unroll 8
    for (int k = 0; k < 32; k++) {
      float4 a  = A4[k],      wv  = W4[k];
      float4 a2 = A4[k + 32], wv2 = W4[k + 32];
      pa = fmaf(a.x,  wv.x,  pa); pa = fmaf(a.y,  wv.y,  pa);
      pa = fmaf(a.z,  wv.z,  pa); pa = fmaf(a.w,  wv.w,  pa);
      qa = fmaf(a2.x, wv2.x, qa); qa = fmaf(a2.y, wv2.y, qa);
      qa = fmaf(a2.z, wv2.z, qa); qa = fmaf(a2.w, wv2.w, qa);
    }
    return pa + qa;
  };

  // ---- pre-stage: Xs <- x[:,0], Wsh <- W0[0] ----
  {
    float4 mu[4], sd[4], ep[4];
    issueW(0, 0, mu, sd, ep);
    #pragma unroll
    for (int p = 0; p < 4; p++) {
      int q = p * NTHR + tid;
      int row = q >> 6, c4 = q & 63;
      *(float4*)&Xs[row][c4 * 4] =
          *((const float4*)(x + ((b0 + row) * L_) * I_) + c4);
    }
    writeW(mu, sd, ep);
  }
  __syncthreads();

  // ---------------- main skewed loop: layer0@tau, layer1@tau-1 ----------------
  for (int tau = 0; tau <= L_; tau++) {
    const int t0 = tau;
    const int t1 = tau - 1;
    const float* h0prev = hb0 + ((tau - 1) & 1) * 32768;
    const float* h1prev = hb1 + (tau & 1) * 32768;
    const bool havenx = (tau + 1 < L_);

    // S1: issue ALL async loads for this iteration (reg-prefetch, T14)
    float4 h0v[4], h1v[4], xn[4];
    float4 mu1v[4], sd1v[4], ep1v[4];
    #pragma unroll
    for (int p = 0; p < 4; p++) {
      int q = p * NTHR + tid;
      int row = q >> 6, c4 = q & 63;
      h0v[p] = ld_cohere(h0prev + (b0 + row) * H_ + c4 * 4);
      h1v[p] = ld_cohere(h1prev + (b0 + row) * H_ + c4 * 4);
    }
    if (tau >= 1) issueW(1, t1, mu1v, sd1v, ep1v);
    if (havenx) {
      #pragma unroll
      for (int p = 0; p < 4; p++) {
        int q = p * NTHR + tid;
        int row = q >> 6, c4 = q & 63;
        xn[p] = *((const float4*)(x + ((b0 + row) * L_ + (tau + 1)) * I_) + c4);
      }
    }

    // S2: layer0 x-half dot (hides the h-exchange latency)
    float acc0 = 0.f;
    if (tau < L_) acc0 = dotp(&Xs[b_l][0], &Wsh[rr][0]);
    __syncthreads();                 // Xs consumed -> safe to overwrite

    // S3: drain asm loads, write h tiles (+ next x)
    vm_drain();
    #pragma unroll
    for (int p = 0; p < 4; p++) {
      int q = p * NTHR + tid;
      int row = q >> 6, c4 = q & 63;
      *(float4*)&H0s[row][c4 * 4] = h0v[p];
      *(float4*)&H1s[row][c4 * 4] = h1v[p];
    }
    if (havenx) {
      #pragma unroll
      for (int p = 0; p < 4; p++) {
        int q = p * NTHR + tid;
        int row = q >> 6, c4 = q & 63;
        *(float4*)&Xs[row][c4 * 4] = xn[p];
      }
    }
    __syncthreads();

    // S4: layer0 h-half dot + in-wave gate exchange + cell0
    if (tau < L_) {
      acc0 += dotp(&H0s[b_l][0], &Wsh[rr][256]);
      acc0 += fmaf(epsb0[t0 * G4_ + jrow], bstd0[jrow], bmu0[jrow]);
      float fg = __shfl_xor(acc0, 1);
      float gg = __shfl_xor(acc0, 2);
      float og = __shfl_xor(acc0, 3);
      if (gq == 0) {
        float si = sigm(acc0), sf = sigm(fg), sg = tanhf(gg), so = sigm(og);
        float cn = fmaf(sf, c0reg, si * sg);
        float h  = so * tanhf(cn);
        c0reg = cn;
        __hip_atomic_store(&hb0[(tau & 1) * 32768 + bglob * H_ + uglob], h,
                           __ATOMIC_RELAXED, __HIP_MEMORY_SCOPE_AGENT);
        if (t0 == L_ - 1) {
          out[HF_OFF + bglob * H_ + uglob] = h;
          out[CF_OFF + bglob * H_ + uglob] = cn;
        }
      }
    }
    __syncthreads();                 // Wsh consumed by layer0

    // S5: refill Wsh with W1[t1] (sources already landed); prefetch W0[tau+1]
    float4 mu0v[4], sd0v[4], ep0v[4];
    if (tau >= 1) writeW(mu1v, sd1v, ep1v);
    if (havenx)  issueW(0, tau + 1, mu0v, sd0v, ep0v);
    __syncthreads();

    // S6: layer1 full-K dot + cell1
    if (tau >= 1) {
      float acc1 = dotp(&H0s[b_l][0], &Wsh[rr][0])
                 + dotp(&H1s[b_l][0], &Wsh[rr][256]);
      acc1 += fmaf(epsb1[t1 * G4_ + jrow], bstd1[jrow], bmu1[jrow]);
      float fg = __shfl_xor(acc1, 1);
      float gg = __shfl_xor(acc1, 2);
      float og = __shfl_xor(acc1, 3);
      if (gq == 0) {
        float si = sigm(acc1), sf = sigm(fg), sg = tanhf(gg), so = sigm(og);
        float cn = fmaf(sf, c1reg, si * sg);
        float h  = so * tanhf(cn);
        c1reg = cn;
        __hip_atomic_store(&hb1[((tau - 1) & 1) * 32768 + bglob * H_ + uglob], h,
                           __ATOMIC_RELAXED, __HIP_MEMORY_SCOPE_AGENT);
        out[(bglob * L_ + t1) * H_ + uglob] = h;
        if (t1 == L_ - 1) {
          out[HF_OFF + (B_ + bglob) * H_ + uglob] = h;
          out[CF_OFF + (B_ + bglob) * H_ + uglob] = cn;
        }
      }
    }
    __syncthreads();                 // Wsh consumed by layer1

    // S7: refill Wsh with W0[tau+1] (compiler waits on mu0v/sd0v/ep0v uses)
    if (havenx) writeW(mu0v, sd0v, ep0v);

    // S8: hierarchical grid barrier (skip after the final exchange)
    if (tau < L_) {
      __builtin_amdgcn_s_waitcnt(0);   // this wave's h stores are at L3
      __syncthreads();                 // all waves drained
      const unsigned tgt = (unsigned)(tau + 1);
      if (tid == 0)
        __hip_atomic_fetch_add(&cnt[(g & 15) << 5], 1u,
                               __ATOMIC_RELAXED, __HIP_MEMORY_SCOPE_AGENT);
      if (g == 0) {
        if (tid < 16) {
          const unsigned t16 = tgt << 4;   // 16 blocks per counter
          while (__hip_atomic_load(&cnt[tid << 5],
                                   __ATOMIC_RELAXED, __HIP_MEMORY_SCOPE_AGENT) < t16)
            __builtin_amdgcn_s_sleep(1);
        }
        __syncthreads();
        if (tid == 0)
          __hip_atomic_store(&cnt[512], tgt,
                             __ATOMIC_RELAXED, __HIP_MEMORY_SCOPE_AGENT);
      } else if (tid == 0) {
        while (__hip_atomic_load(&cnt[512],
                                 __ATOMIC_RELAXED, __HIP_MEMORY_SCOPE_AGENT) < tgt)
          __builtin_amdgcn_s_sleep(1);
      }
      __syncthreads();
    }
  }

  // ---------------- final KL reduce ----------------
  if (g == 0) {
    red[tid] = (tid < NBLK) ? klp[tid] : 0.f;
    __syncthreads();
    for (int s = NTHR / 2; s > 0; s >>= 1) {
      if (tid < s) red[tid] += red[tid + s];
      __syncthreads();
    }
    if (tid == 0) out[KL_OFF] = red[0];
  }
}

extern "C" void kernel_launch(void* const* d_in, const int* in_sizes, int n_in,
                              void* d_out, int out_size, void* d_ws, size_t ws_size,
                              hipStream_t stream) {
  const float* x     = (const float*)d_in[0];
  const float* wmu0  = (const float*)d_in[1];
  const float* wlv0  = (const float*)d_in[2];
  const float* bmu0  = (const float*)d_in[3];
  const float* blv0  = (const float*)d_in[4];
  const float* wmu1  = (const float*)d_in[5];
  const float* wlv1  = (const float*)d_in[6];
  const float* bmu1  = (const float*)d_in[7];
  const float* blv1  = (const float*)d_in[8];
  const float* epsw0 = (const float*)d_in[9];
  const float* epsb0 = (const float*)d_in[10];
  const float* epsw1 = (const float*)d_in[11];
  const float* epsb1 = (const float*)d_in[12];
  float* out = (float*)d_out;
  float* ws  = (float*)d_ws;

  void* args[] = {
    (void*)&x,
    (void*)&wmu0, (void*)&wlv0, (void*)&bmu0, (void*)&blv0,
    (void*)&wmu1, (void*)&wlv1, (void*)&bmu1, (void*)&blv1,
    (void*)&epsw0, (void*)&epsb0, (void*)&epsw1, (void*)&epsb1,
    (void*)&out, (void*)&ws
  };
  hipLaunchCooperativeKernel((void*)vlstm, dim3(NBLK), dim3(NTHR),
                             (void**)args, 0, stream);
}

// Round 3
// 2612.308 us; speedup vs baseline: 1.3424x; 1.1768x over previous
//
#include <hip/hip_runtime.h>
#include <hip/hip_cooperative_groups.h>
#include <cmath>

namespace cg = cooperative_groups;

// Problem constants
constexpr int B_  = 128, L_ = 128, I_ = 256, H_ = 256;
constexpr int G4_ = 1024;          // 4*H
constexpr int K_  = 512;           // I+H == H+H
constexpr int NBLK = 256;          // 64 unit-tiles x 4 batch-tiles (1 block/CU)
constexpr int NTHR = 512;          // 8 waves/CU
constexpr int BT = 32;             // batch rows per WG
constexpr int GR = 16;             // gate rows per WG (4 units x 4 gates)

// ws layout (float offsets)
constexpr int WSTD0 = 0;
constexpr int WSTD1 = 524288;
constexpr int BSTD0 = 1048576;
constexpr int BSTD1 = BSTD0 + 1024;
constexpr int HB0   = BSTD1 + 1024;   // 2 ping-pong buffers of 128*256
constexpr int HB1   = HB0 + 65536;
constexpr int KLP   = HB1 + 65536;    // 256 partials
constexpr int CNT   = KLP + 256;      // 16 counters (stride 32 u32) + epoch @ [512]

// out layout (float offsets)
constexpr int HF_OFF = B_*L_*H_;           // 4194304
constexpr int CF_OFF = HF_OFF + 2*B_*H_;   // 4259840
constexpr int KL_OFF = CF_OFF + 2*B_*H_;   // 4325376

// eps tile held in named members only — never address-taken, never an array
struct F44 { float4 a, b, c, d; };

__device__ __forceinline__ float sigm(float v) { return 1.0f / (1.0f + expf(-v)); }

// Coherent (L1/L2-bypassing) 16B load — data comes from L3, which agent-scope
// atomic stores write through to. Consumer must drain vmcnt before use.
__device__ __forceinline__ float4 ld_cohere(const float* p) {
  float4 v;
  asm volatile("global_load_dwordx4 %0, %1, off sc0 sc1"
               : "=v"(v) : "v"(p) : "memory");
  return v;
}
__device__ __forceinline__ void vm_drain() {
  asm volatile("s_waitcnt vmcnt(0)" ::: "memory");
}
// LDS-only barrier: does NOT drain vmcnt, so global prefetches stay in flight
// across it. "memory" clobbers fence compiler reordering of memory ops.
__device__ __forceinline__ void bar_lds() {
  asm volatile("s_waitcnt lgkmcnt(0)" ::: "memory");
  __builtin_amdgcn_s_barrier();
  asm volatile("" ::: "memory");
}

__global__ __launch_bounds__(NTHR, 1) void vlstm(
    const float* __restrict__ x,
    const float* __restrict__ wmu0, const float* __restrict__ wlv0,
    const float* __restrict__ bmu0, const float* __restrict__ blv0,
    const float* __restrict__ wmu1, const float* __restrict__ wlv1,
    const float* __restrict__ bmu1, const float* __restrict__ blv1,
    const float* __restrict__ epsw0, const float* __restrict__ epsb0,
    const float* __restrict__ epsw1, const float* __restrict__ epsb1,
    float* __restrict__ out, float* __restrict__ ws)
{
  cg::grid_group grid = cg::this_grid();
  const int tid = threadIdx.x;
  const int g   = blockIdx.x;
  const int bt  = g >> 6;            // 0..3
  const int ut  = g & 63;            // 0..63
  const int b0  = bt * BT;
  const int u0  = ut * 4;

  // pad 4: row stride mod 32 banks = 4 -> 8-row wave groups hit disjoint banks
  __shared__ float Xs [BT][260];     // x_t tile (pre-staged one step ahead)
  __shared__ float H0s[BT][260];     // h0prev tile
  __shared__ float H1s[BT][260];     // h1prev tile
  __shared__ float Wsh[GR][516];     // full-K W tile, single-buffered, reg-refilled
  __shared__ float red[NTHR];

  float* wstd0 = ws + WSTD0;
  float* wstd1 = ws + WSTD1;
  float* bstd0 = ws + BSTD0;
  float* bstd1 = ws + BSTD1;
  float* hb0   = ws + HB0;
  float* hb1   = ws + HB1;
  float* klp   = ws + KLP;
  unsigned* cnt = (unsigned*)(ws + CNT);   // [0..480 step 32] arrive; [512] epoch

  // ---------------- pre-phase: stds, KL partials, zero h buffers ----------------
  const int gid = g * NTHR + tid;
  const int gsz = NBLK * NTHR;   // 131072
  float kl = 0.f;
  for (int i = gid; i < 524288; i += gsz) {
    float l0 = wlv0[i], l1 = wlv1[i];
    float m0 = wmu0[i], m1 = wmu1[i];
    wstd0[i] = expf(0.5f * l0);
    wstd1[i] = expf(0.5f * l1);
    kl += 0.5f * (m0*m0 + expf(l0) - l0) + 0.5f * (m1*m1 + expf(l1) - l1);
  }
  for (int i = gid; i < G4_; i += gsz) {
    float l0 = blv0[i], l1 = blv1[i];
    float m0 = bmu0[i], m1 = bmu1[i];
    bstd0[i] = expf(0.5f * l0);
    bstd1[i] = expf(0.5f * l1);
    kl += 0.5f * (m0*m0 + expf(l0) - l0) + 0.5f * (m1*m1 + expf(l1) - l1);
  }
  for (int i = gid; i < 32768; i += gsz) {
    hb0[i] = 0.f; hb0[32768 + i] = 0.f;
    hb1[i] = 0.f; hb1[32768 + i] = 0.f;
  }
  if (gid < 544) cnt[gid] = 0u;
  red[tid] = kl;
  __syncthreads();
  for (int s = NTHR / 2; s > 0; s >>= 1) {
    if (tid < s) red[tid] += red[tid + s];
    __syncthreads();
  }
  if (tid == 0) klp[g] = red[0];
  grid.sync();   // publishes wstd/bstd, hb zeros, klp, counters device-wide

  // compute mapping: wave = 8 batch rows x 8 gate rows
  const int wid  = tid >> 6;
  const int lane = tid & 63;
  const int b_l  = ((wid & 3) << 3) | (lane >> 3);      // 0..31
  const int rr   = ((wid >> 2) << 3) | (lane & 7);      // 0..15
  const int gq   = lane & 3;                            // gate: 0=i 1=f 2=g 3=o
  const int un   = rr >> 2;                             // unit 0..3
  const int jrow = gq * H_ + u0 + un;                   // global gate row
  const int bglob = b0 + b_l;
  const int uglob = u0 + un;

  // bias mu/std are t-invariant: hoist
  const float bm0 = bmu0[jrow], bs0 = bstd0[jrow];
  const float bm1 = bmu1[jrow], bs1 = bstd1[jrow];

  float c0reg = 0.f, c1reg = 0.f;

  // ---- per-thread W-staging constants (p = 0..3, q = p*NTHR+tid) ----
  int q0 = tid,            r0w = q0 >> 7, c0w = q0 & 127;
  int q1 = NTHR + tid,     r1w = q1 >> 7, c1w = q1 & 127;
  int q2 = 2*NTHR + tid,   r2w = q2 >> 7, c2w = q2 & 127;
  int q3 = 3*NTHR + tid,   r3w = q3 >> 7, c3w = q3 & 127;
  const int wOff0 = ((r0w & 3) * H_ + u0 + (r0w >> 2)) * K_ + c0w * 4;
  const int wOff1 = ((r1w & 3) * H_ + u0 + (r1w >> 2)) * K_ + c1w * 4;
  const int wOff2 = ((r2w & 3) * H_ + u0 + (r2w >> 2)) * K_ + c2w * 4;
  const int wOff3 = ((r3w & 3) * H_ + u0 + (r3w >> 2)) * K_ + c3w * 4;
  float* wdst0 = &Wsh[r0w][c0w * 4];
  float* wdst1 = &Wsh[r1w][c1w * 4];
  float* wdst2 = &Wsh[r2w][c2w * 4];
  float* wdst3 = &Wsh[r3w][c3w * 4];

  // ---- per-thread H/X-tile staging constants ----
  int hq0 = tid,          hr0 = hq0 >> 6, hc0 = hq0 & 63;
  int hq1 = NTHR + tid,   hr1 = hq1 >> 6, hc1 = hq1 & 63;
  int hq2 = 2*NTHR + tid, hr2 = hq2 >> 6, hc2 = hq2 & 63;
  int hq3 = 3*NTHR + tid, hr3 = hq3 >> 6, hc3 = hq3 & 63;
  const int hOff0 = (b0 + hr0) * H_ + hc0 * 4;
  const int hOff1 = (b0 + hr1) * H_ + hc1 * 4;
  const int hOff2 = (b0 + hr2) * H_ + hc2 * 4;
  const int hOff3 = (b0 + hr3) * H_ + hc3 * 4;
  const size_t xOff0 = (size_t)(b0 + hr0) * L_ * I_ + hc0 * 4;
  const size_t xOff1 = (size_t)(b0 + hr1) * L_ * I_ + hc1 * 4;
  const size_t xOff2 = (size_t)(b0 + hr2) * L_ * I_ + hc2 * 4;
  const size_t xOff3 = (size_t)(b0 + hr3) * L_ * I_ + hc3 * 4;
  float* h0d0 = &H0s[hr0][hc0*4]; float* h1d0 = &H1s[hr0][hc0*4]; float* xd0 = &Xs[hr0][hc0*4];
  float* h0d1 = &H0s[hr1][hc1*4]; float* h1d1 = &H1s[hr1][hc1*4]; float* xd1 = &Xs[hr1][hc1*4];
  float* h0d2 = &H0s[hr2][hc2*4]; float* h1d2 = &H1s[hr2][hc2*4]; float* xd2 = &Xs[hr2][hc2*4];
  float* h0d3 = &H0s[hr3][hc3*4]; float* h1d3 = &H1s[hr3][hc3*4]; float* xd3 = &Xs[hr3][hc3*4];

  auto loadEps = [&](const float* eb) -> F44 {
    F44 r;
    r.a = *(const float4*)(eb + wOff0);
    r.b = *(const float4*)(eb + wOff1);
    r.c = *(const float4*)(eb + wOff2);
    r.d = *(const float4*)(eb + wOff3);
    return r;
  };
  // w = mu + eps*std; mu/std loaded here (L2-resident: same addresses every t)
  auto writeW = [&](const float* wmu, const float* wsd, F44 e) {
    float4 m, s, w;
    m = *(const float4*)(wmu + wOff0); s = *(const float4*)(wsd + wOff0);
    w.x = fmaf(e.a.x, s.x, m.x); w.y = fmaf(e.a.y, s.y, m.y);
    w.z = fmaf(e.a.z, s.z, m.z); w.w = fmaf(e.a.w, s.w, m.w);
    *(float4*)wdst0 = w;
    m = *(const float4*)(wmu + wOff1); s = *(const float4*)(wsd + wOff1);
    w.x = fmaf(e.b.x, s.x, m.x); w.y = fmaf(e.b.y, s.y, m.y);
    w.z = fmaf(e.b.z, s.z, m.z); w.w = fmaf(e.b.w, s.w, m.w);
    *(float4*)wdst1 = w;
    m = *(const float4*)(wmu + wOff2); s = *(const float4*)(wsd + wOff2);
    w.x = fmaf(e.c.x, s.x, m.x); w.y = fmaf(e.c.y, s.y, m.y);
    w.z = fmaf(e.c.z, s.z, m.z); w.w = fmaf(e.c.w, s.w, m.w);
    *(float4*)wdst2 = w;
    m = *(const float4*)(wmu + wOff3); s = *(const float4*)(wsd + wOff3);
    w.x = fmaf(e.d.x, s.x, m.x); w.y = fmaf(e.d.y, s.y, m.y);
    w.z = fmaf(e.d.z, s.z, m.z); w.w = fmaf(e.d.w, s.w, m.w);
    *(float4*)wdst3 = w;
  };
  auto dotp = [&](const float* Ap, const float* Wp) -> float {
    const float4* A4 = (const float4*)Ap;
    const float4* W4 = (const float4*)Wp;
    float pa = 0.f, qa = 0.f;
    #pragma unroll 8
    for (int k = 0; k < 32; k++) {
      float4 a  = A4[k],      wv  = W4[k];
      float4 a2 = A4[k + 32], wv2 = W4[k + 32];
      pa = fmaf(a.x,  wv.x,  pa); pa = fmaf(a.y,  wv.y,  pa);
      pa = fmaf(a.z,  wv.z,  pa); pa = fmaf(a.w,  wv.w,  pa);
      qa = fmaf(a2.x, wv2.x, qa); qa = fmaf(a2.y, wv2.y, qa);
      qa = fmaf(a2.z, wv2.z, qa); qa = fmaf(a2.w, wv2.w, qa);
    }
    return pa + qa;
  };

  // ---- pre-stage: Xs <- x[:,0], Wsh <- W0[0] ----
  {
    *(float4*)xd0 = *(const float4*)(x + xOff0);
    *(float4*)xd1 = *(const float4*)(x + xOff1);
    *(float4*)xd2 = *(const float4*)(x + xOff2);
    *(float4*)xd3 = *(const float4*)(x + xOff3);
    F44 e = loadEps(epsw0);
    writeW(wmu0, wstd0, e);
  }
  __syncthreads();

  // ---------------- main skewed loop: layer0@tau, layer1@tau-1 ----------------
  for (int tau = 0; tau <= L_; tau++) {
    const int t0 = tau;
    const int t1 = tau - 1;
    const float* h0prev = hb0 + ((tau - 1) & 1) * 32768;
    const float* h1prev = hb1 + (tau & 1) * 32768;
    const bool have0  = (tau < L_);
    const bool have1  = (tau >= 1);
    const bool havenx = (tau + 1 < L_);

    // fresh (opaque) copies of t-invariant W base pointers: blocks LICM from
    // hoisting 32 loop-invariant float4 loads into permanently-live VGPRs
    const float* wmu0v = wmu0; const float* wsd0v = wstd0;
    const float* wmu1v = wmu1; const float* wsd1v = wstd1;
    asm volatile("" : "+s"(wmu0v), "+s"(wsd0v), "+s"(wmu1v), "+s"(wsd1v));

    // S1: coherent h loads + x[t+1] loads (in flight through S2's dot)
    float4 h00 = ld_cohere(h0prev + hOff0);
    float4 h01 = ld_cohere(h0prev + hOff1);
    float4 h02 = ld_cohere(h0prev + hOff2);
    float4 h03 = ld_cohere(h0prev + hOff3);
    float4 h10 = ld_cohere(h1prev + hOff0);
    float4 h11 = ld_cohere(h1prev + hOff1);
    float4 h12 = ld_cohere(h1prev + hOff2);
    float4 h13 = ld_cohere(h1prev + hOff3);
    float4 xn0, xn1, xn2, xn3;
    if (havenx) {
      const size_t xo = (size_t)(tau + 1) * I_;
      xn0 = *(const float4*)(x + xOff0 + xo);
      xn1 = *(const float4*)(x + xOff1 + xo);
      xn2 = *(const float4*)(x + xOff2 + xo);
      xn3 = *(const float4*)(x + xOff3 + xo);
    }

    // S2: layer0 x-half dot (hides h-exchange + x-next latency)
    float acc0 = 0.f;
    if (have0) acc0 = dotp(&Xs[b_l][0], &Wsh[rr][0]);
    bar_lds();                        // Xs consumed; vm prefetches stay in flight

    // S3: drain loads, write H tiles + next-x tile; issue eps1 prefetch
    vm_drain();
    *(float4*)h0d0 = h00; *(float4*)h1d0 = h10;
    *(float4*)h0d1 = h01; *(float4*)h1d1 = h11;
    *(float4*)h0d2 = h02; *(float4*)h1d2 = h12;
    *(float4*)h0d3 = h03; *(float4*)h1d3 = h13;
    if (havenx) {
      *(float4*)xd0 = xn0;
      *(float4*)xd1 = xn1;
      *(float4*)xd2 = xn2;
      *(float4*)xd3 = xn3;
    }
    F44 e1;
    if (have1) e1 = loadEps(epsw1 + (size_t)t1 * 524288);   // flies over S4
    bar_lds();                        // H/X tiles visible; eps1 in flight

    // S4: layer0 h-half dot + in-wave gate exchange + cell0
    if (have0) {
      acc0 += dotp(&H0s[b_l][0], &Wsh[rr][256]);
      acc0 += fmaf(epsb0[t0 * G4_ + jrow], bs0, bm0);
      float fg = __shfl_xor(acc0, 1);
      float gg = __shfl_xor(acc0, 2);
      float og = __shfl_xor(acc0, 3);
      if (gq == 0) {
        float si = sigm(acc0), sf = sigm(fg), sg = tanhf(gg), so = sigm(og);
        float cn = fmaf(sf, c0reg, si * sg);
        float h  = so * tanhf(cn);
        c0reg = cn;
        __hip_atomic_store(&hb0[(tau & 1) * 32768 + bglob * H_ + uglob], h,
                           __ATOMIC_RELAXED, __HIP_MEMORY_SCOPE_AGENT);
        if (t0 == L_ - 1) {
          out[HF_OFF + bglob * H_ + uglob] = h;
          out[CF_OFF + bglob * H_ + uglob] = cn;
        }
      }
    }
    bar_lds();                        // Wsh consumed by layer0

    // S5: refill Wsh with W1[t1]; prefetch eps0[tau+1] (in flight thru S6)
    if (have1) writeW(wmu1v, wsd1v, e1);
    F44 e0;
    if (havenx) e0 = loadEps(epsw0 + (size_t)(tau + 1) * 524288);
    bar_lds();                        // Wsh ready; eps0 still in flight

    // S6: layer1 full-K dot + cell1
    if (have1) {
      float acc1 = dotp(&H0s[b_l][0], &Wsh[rr][0])
                 + dotp(&H1s[b_l][0], &Wsh[rr][256]);
      acc1 += fmaf(epsb1[t1 * G4_ + jrow], bs1, bm1);
      float fg = __shfl_xor(acc1, 1);
      float gg = __shfl_xor(acc1, 2);
      float og = __shfl_xor(acc1, 3);
      if (gq == 0) {
        float si = sigm(acc1), sf = sigm(fg), sg = tanhf(gg), so = sigm(og);
        float cn = fmaf(sf, c1reg, si * sg);
        float h  = so * tanhf(cn);
        c1reg = cn;
        __hip_atomic_store(&hb1[((tau - 1) & 1) * 32768 + bglob * H_ + uglob], h,
                           __ATOMIC_RELAXED, __HIP_MEMORY_SCOPE_AGENT);
        out[(bglob * L_ + t1) * H_ + uglob] = h;
        if (t1 == L_ - 1) {
          out[HF_OFF + (B_ + bglob) * H_ + uglob] = h;
          out[CF_OFF + (B_ + bglob) * H_ + uglob] = cn;
        }
      }
    }
    __syncthreads();   // FULL sync: Wsh free + this block's h stores drained

    // S7: refill Wsh with W0[tau+1] (eps0 landed; mu/std from L2)
    if (havenx) writeW(wmu0v, wsd0v, e0);

    // S8: hierarchical grid barrier (skip after the final exchange)
    if (tau < L_) {
      const unsigned tgt = (unsigned)(tau + 1);
      if (tid == 0)
        __hip_atomic_fetch_add(&cnt[(g & 15) << 5], 1u,
                               __ATOMIC_RELAXED, __HIP_MEMORY_SCOPE_AGENT);
      if (g == 0) {
        if (tid < 16) {
          const unsigned t16 = tgt << 4;   // 16 blocks per counter
          while (__hip_atomic_load(&cnt[tid << 5],
                                   __ATOMIC_RELAXED, __HIP_MEMORY_SCOPE_AGENT) < t16)
            __builtin_amdgcn_s_sleep(1);
        }
        __syncthreads();
        if (tid == 0)
          __hip_atomic_store(&cnt[512], tgt,
                             __ATOMIC_RELAXED, __HIP_MEMORY_SCOPE_AGENT);
      } else if (tid == 0) {
        while (__hip_atomic_load(&cnt[512],
                                 __ATOMIC_RELAXED, __HIP_MEMORY_SCOPE_AGENT) < tgt)
          __builtin_amdgcn_s_sleep(1);
      }
      __syncthreads();   // FULL: epoch seen + Wsh(S7) visible for next S2
    }
  }

  // ---------------- final KL reduce ----------------
  if (g == 0) {
    red[tid] = (tid < NBLK) ? klp[tid] : 0.f;
    __syncthreads();
    for (int s = NTHR / 2; s > 0; s >>= 1) {
      if (tid < s) red[tid] += red[tid + s];
      __syncthreads();
    }
    if (tid == 0) out[KL_OFF] = red[0];
  }
}

extern "C" void kernel_launch(void* const* d_in, const int* in_sizes, int n_in,
                              void* d_out, int out_size, void* d_ws, size_t ws_size,
                              hipStream_t stream) {
  const float* x     = (const float*)d_in[0];
  const float* wmu0  = (const float*)d_in[1];
  const float* wlv0  = (const float*)d_in[2];
  const float* bmu0  = (const float*)d_in[3];
  const float* blv0  = (const float*)d_in[4];
  const float* wmu1  = (const float*)d_in[5];
  const float* wlv1  = (const float*)d_in[6];
  const float* bmu1  = (const float*)d_in[7];
  const float* blv1  = (const float*)d_in[8];
  const float* epsw0 = (const float*)d_in[9];
  const float* epsb0 = (const float*)d_in[10];
  const float* epsw1 = (const float*)d_in[11];
  const float* epsb1 = (const float*)d_in[12];
  float* out = (float*)d_out;
  float* ws  = (float*)d_ws;

  void* args[] = {
    (void*)&x,
    (void*)&wmu0, (void*)&wlv0, (void*)&bmu0, (void*)&blv0,
    (void*)&wmu1, (void*)&wlv1, (void*)&bmu1, (void*)&blv1,
    (void*)&epsw0, (void*)&epsb0, (void*)&epsw1, (void*)&epsb1,
    (void*)&out, (void*)&ws
  };
  hipLaunchCooperativeKernel((void*)vlstm, dim3(NBLK), dim3(NTHR),
                             (void**)args, 0, stream);
}